// Round 14
// baseline (295.376 us; speedup 1.0000x reference)
//
#include <hip/hip_runtime.h>
#include <hip/hip_bf16.h>
#include <math.h>

// Problem dims (fixed by reference)
#define B_ROWS 8192
#define D_IN   256
#define H1_DIM 512
#define H2_DIM 256
#define D_OUT  64
#define EPSF   1e-12f
#define THRESH 0.9f

typedef __attribute__((ext_vector_type(8))) short short8;   // 8 bf16 = 4 VGPR
typedef __attribute__((ext_vector_type(4))) float f32x4;

// fast tanh via hardware exp: tanh(|x|) = (1-e^{-2|x|})/(1+e^{-2|x|}), ~1e-7 rel err
__device__ inline float tanh_fast(float xx) {
  const float ax = fabsf(xx);
  const float t = __expf(-2.0f * ax);
  const float r = (1.0f - t) / (1.0f + t);
  return xx < 0.0f ? -r : r;
}

// split fp32x8 -> bf16 hi + bf16 mid (residual), fragment-packed
__device__ inline void splitf8(float4 a, float4 b, short8& h, short8& m) {
  float v[8] = {a.x, a.y, a.z, a.w, b.x, b.y, b.z, b.w};
  short h8[8], m8[8];
#pragma unroll
  for (int e = 0; e < 8; ++e) {
    __hip_bfloat16 hb = __float2bfloat16(v[e]);
    float hf = __bfloat162float(hb);
    __hip_bfloat16 mb = __float2bfloat16(v[e] - hf);
    h8[e] = *(short*)&hb;
    m8[e] = *(short*)&mb;
  }
  h = *(short8*)h8;
  m = *(short8*)m8;
}

// read 8 logical-consecutive floats at (row, kl) from an XOR-swizzled LDS buf.
// swizzle: dword index ^= (row&7)<<2 (16B-slot spread -> conflict-free b128)
__device__ inline void rd8_swz(const float* buf, int S, int row, int kl,
                               float4& a, float4& b) {
  const int xr = (row & 7) << 2;
  a = *(const float4*)&buf[(row * S + kl) ^ xr];
  b = *(const float4*)&buf[(row * S + kl + 4) ^ xr];
}

// ---------------- weight pre-pack (fragment-major bf16 hi/mid) ----------------
__device__ inline void pack8(const float* __restrict__ src, short* __restrict__ dh,
                             short* __restrict__ dm, int t, int C, int lgq) {
  const int lane = t & 63;
  const int g = t >> 6;
  const int q = g & ((1 << lgq) - 1);
  const int I = g >> lgq;
  const int row = I * 16 + (lane & 15);
  const int k0 = q * 32 + ((lane >> 4) << 3);
  const float* p = src + (size_t)row * C + k0;
  short8 hh, mm;
  splitf8(*(const float4*)p, *(const float4*)(p + 4), hh, mm);
  *(short8*)(dh + (size_t)t * 8) = hh;
  *(short8*)(dm + (size_t)t * 8) = mm;
}

__global__ __launch_bounds__(256)
void wpack(const float* __restrict__ W1, const float* __restrict__ W2,
           const float* __restrict__ W3,
           short* w1h, short* w1m, short* w2h, short* w2m,
           short* w3h, short* w3m) {
  const int b = blockIdx.x, tid = threadIdx.x;
  if (b < 64)        pack8(W1, w1h, w1m, b * 256 + tid, 256, 3);
  else if (b < 128)  pack8(W2, w2h, w2m, (b - 64) * 256 + tid, 512, 4);
  else               pack8(W3, w3h, w3m, (b - 128) * 256 + tid, 256, 3);
}

// ---------------- fully fused MLP, 16-row blocks (R11-exact, (512,4)) ----------------
__global__ __launch_bounds__(512, 4)
void fused_mlp16(const float* __restrict__ x,
                 const short* __restrict__ w1h, const short* __restrict__ w1m,
                 const float* __restrict__ b1,
                 const short* __restrict__ w2h, const short* __restrict__ w2m,
                 const float* __restrict__ b2,
                 const short* __restrict__ w3h, const short* __restrict__ w3m,
                 const float* __restrict__ b3,
                 float* __restrict__ out, short* __restrict__ vph,
                 short* __restrict__ vpm, float* __restrict__ res) {
  __shared__ __align__(16) char smem[49152];
  short* xph   = (short*)smem;                // 8KB
  short* xpm   = (short*)(smem + 8192);       // 8KB
  float* wbuf1 = (float*)smem;                // 16KB
  float* wbuf3 = (float*)smem;                // 4KB
  short* h1h   = (short*)(smem + 16384);      // 16KB
  short* h1m   = (short*)(smem + 32768);      // 16KB
  float* wbuf2 = (float*)(smem + 16384);      // 16KB
  short* h2ph  = (short*)(smem + 32768);      // 8KB
  short* h2pm  = (short*)(smem + 40960);      // 8KB
  __shared__ float nsum[16];
  __shared__ float invn[16];

  const int tid = threadIdx.x;
  const int wave = tid >> 6, lane = tid & 63;
  const int r0 = blockIdx.x * 16;
  const int col16 = lane & 15;
  const int rbase = (lane >> 4) << 2;   // C-layout row base

  // zero this block's res rows (harness poisons res): 16*64 = 256 float4
  if (tid < 256) {
    float4* rz = (float4*)(res + (size_t)r0 * D_OUT);
    rz[tid] = make_float4(0.f, 0.f, 0.f, 0.f);
  }

  // ---- pack x block (16x256 fp32 -> frag hi/mid): 512 units, 1/thread ----
  {
    const int lu = tid & 63, q = tid >> 6;
    const float* p = x + (size_t)(r0 + (lu & 15)) * D_IN + q * 32 + ((lu >> 4) << 3);
    short8 hh, mm;
    splitf8(*(const float4*)p, *(const float4*)(p + 4), hh, mm);
    const int off = (q * 64 + lu) * 8;
    *(short8*)(xph + off) = hh;
    *(short8*)(xpm + off) = mm;
  }
  __syncthreads();

  // ---- layer1: h1 = tanh(x @ W1^T + b1), N=512; wave owns 4 j-tiles ----
  f32x4 acc1[4];
#pragma unroll
  for (int jj = 0; jj < 4; ++jj) acc1[jj] = (f32x4){0.f, 0.f, 0.f, 0.f};
#pragma unroll 4
  for (int q = 0; q < 8; ++q) {
    const int aoff = (q * 64 + lane) * 8;
    const short8 Ah = *(const short8*)(xph + aoff);
    const short8 Am = *(const short8*)(xpm + aoff);
#pragma unroll
    for (int jj = 0; jj < 4; ++jj) {
      const int boff = (((wave * 4 + jj) * 8 + q) * 64 + lane) * 8;
      const short8 Bh = *(const short8*)(w1h + boff);
      const short8 Bm = *(const short8*)(w1m + boff);
      acc1[jj] = __builtin_amdgcn_mfma_f32_16x16x32_bf16(Ah, Bh, acc1[jj], 0, 0, 0);
      acc1[jj] = __builtin_amdgcn_mfma_f32_16x16x32_bf16(Ah, Bm, acc1[jj], 0, 0, 0);
      acc1[jj] = __builtin_amdgcn_mfma_f32_16x16x32_bf16(Am, Bh, acc1[jj], 0, 0, 0);
    }
  }
  __syncthreads();   // xp dead; [0,16K) becomes wbuf1

  // ---- L1 epilogue: two 256-col halves through swizzled wbuf1 ----
  float bv1[4];
#pragma unroll
  for (int jj = 0; jj < 4; ++jj) bv1[jj] = b1[(wave * 4 + jj) * 16 + col16];
#pragma unroll
  for (int h = 0; h < 2; ++h) {
    if ((wave >> 2) == h) {
#pragma unroll
      for (int jj = 0; jj < 4; ++jj)
#pragma unroll
        for (int r = 0; r < 4; ++r) {
          const int row = rbase + r;
          const int col = ((wave & 3) * 4 + jj) * 16 + col16;   // [0,256)
          wbuf1[(row * 256 + col) ^ ((row & 7) << 2)] = tanh_fast(acc1[jj][r] + bv1[jj]);
        }
    }
    __syncthreads();
    {
      const int lu = tid & 63, ql = tid >> 6;
      const int row = lu & 15, kl = ql * 32 + ((lu >> 4) << 3);
      float4 a, b;
      rd8_swz(wbuf1, 256, row, kl, a, b);
      short8 hh, mm;
      splitf8(a, b, hh, mm);
      const int off = ((h * 8 + ql) * 64 + lu) * 8;
      *(short8*)(h1h + off) = hh;
      *(short8*)(h1m + off) = mm;
    }
    __syncthreads();
  }

  // ---- layer2: h2 = tanh(h1 @ W2^T + b2), N=256; wave owns 2 j-tiles ----
  f32x4 acc2[2];
#pragma unroll
  for (int jj = 0; jj < 2; ++jj) acc2[jj] = (f32x4){0.f, 0.f, 0.f, 0.f};
#pragma unroll 4
  for (int q = 0; q < 16; ++q) {
    const int aoff = (q * 64 + lane) * 8;
    const short8 Ah = *(const short8*)(h1h + aoff);
    const short8 Am = *(const short8*)(h1m + aoff);
#pragma unroll
    for (int jj = 0; jj < 2; ++jj) {
      const int boff = (((wave * 2 + jj) * 16 + q) * 64 + lane) * 8;
      const short8 Bh = *(const short8*)(w2h + boff);
      const short8 Bm = *(const short8*)(w2m + boff);
      acc2[jj] = __builtin_amdgcn_mfma_f32_16x16x32_bf16(Ah, Bh, acc2[jj], 0, 0, 0);
      acc2[jj] = __builtin_amdgcn_mfma_f32_16x16x32_bf16(Ah, Bm, acc2[jj], 0, 0, 0);
      acc2[jj] = __builtin_amdgcn_mfma_f32_16x16x32_bf16(Am, Bh, acc2[jj], 0, 0, 0);
    }
  }
  __syncthreads();   // h1 dead; [16K,32K) becomes wbuf2

  // ---- L2 epilogue ----
  {
    float bv2[2];
#pragma unroll
    for (int jj = 0; jj < 2; ++jj) bv2[jj] = b2[(wave * 2 + jj) * 16 + col16];
#pragma unroll
    for (int jj = 0; jj < 2; ++jj)
#pragma unroll
      for (int r = 0; r < 4; ++r) {
        const int row = rbase + r;
        const int col = (wave * 2 + jj) * 16 + col16;   // [0,256)
        wbuf2[(row * 256 + col) ^ ((row & 7) << 2)] = tanh_fast(acc2[jj][r] + bv2[jj]);
      }
  }
  __syncthreads();
  {
    const int lu = tid & 63, ql = tid >> 6;
    const int row = lu & 15, kl = ql * 32 + ((lu >> 4) << 3);
    float4 a, b;
    rd8_swz(wbuf2, 256, row, kl, a, b);
    short8 hh, mm;
    splitf8(a, b, hh, mm);
    const int off = (ql * 64 + lu) * 8;
    *(short8*)(h2ph + off) = hh;
    *(short8*)(h2pm + off) = mm;
  }
  __syncthreads();

  // ---- layer3: out = h2 @ W3^T + b3, N=64; waves 0-3 ----
  if (wave < 4) {
    f32x4 acc3 = (f32x4){0.f, 0.f, 0.f, 0.f};
#pragma unroll 4
    for (int q = 0; q < 8; ++q) {
      const int aoff = (q * 64 + lane) * 8;
      const short8 Ah = *(const short8*)(h2ph + aoff);
      const short8 Am = *(const short8*)(h2pm + aoff);
      const int boff = ((wave * 8 + q) * 64 + lane) * 8;
      const short8 Bh = *(const short8*)(w3h + boff);
      const short8 Bm = *(const short8*)(w3m + boff);
      acc3 = __builtin_amdgcn_mfma_f32_16x16x32_bf16(Ah, Bh, acc3, 0, 0, 0);
      acc3 = __builtin_amdgcn_mfma_f32_16x16x32_bf16(Ah, Bm, acc3, 0, 0, 0);
      acc3 = __builtin_amdgcn_mfma_f32_16x16x32_bf16(Am, Bh, acc3, 0, 0, 0);
    }
    const float bv3 = b3[wave * 16 + col16];
#pragma unroll
    for (int r = 0; r < 4; ++r) {
      const int row = rbase + r;
      const int col = wave * 16 + col16;   // [0,64)
      wbuf3[(row * 64 + col) ^ ((row & 7) << 2)] = acc3[r] + bv3;
    }
  }
  __syncthreads();

  // ---- row norms: 16 threads/row x 4 cols ----
  if (tid < 256) {
    const int row = tid >> 4, c4 = (tid & 15) * 4;
    const float4 a = *(const float4*)&wbuf3[(row * 64 + c4) ^ ((row & 7) << 2)];
    float s = a.x * a.x + a.y * a.y + a.z * a.z + a.w * a.w;
    s += __shfl_xor(s, 1, 64);
    s += __shfl_xor(s, 2, 64);
    s += __shfl_xor(s, 4, 64);
    s += __shfl_xor(s, 8, 64);
    if ((tid & 15) == 0) nsum[row] = s;
  }
  __syncthreads();
  if (tid < 16) invn[tid] = 1.0f / (sqrtf(nsum[tid]) + EPSF);
  __syncthreads();

  // ---- write out (fp32) ----
  if (tid < 256) {
    const int row = tid >> 4, c4 = (tid & 15) * 4;
    *(float4*)(out + (size_t)(r0 + row) * D_OUT + c4) =
        *(const float4*)&wbuf3[(row * 64 + c4) ^ ((row & 7) << 2)];
  }
  // ---- write normalized split-pack vph/vpm (gram operand) ----
  if (tid < 128) {
    const int lu = tid & 63, ql = tid >> 6;
    const int row = lu & 15, kl = ql * 32 + ((lu >> 4) << 3);
    const float sc = invn[row];
    float4 a, b;
    rd8_swz(wbuf3, 64, row, kl, a, b);
    a.x *= sc; a.y *= sc; a.z *= sc; a.w *= sc;
    b.x *= sc; b.y *= sc; b.z *= sc; b.w *= sc;
    short8 hh, mm;
    splitf8(a, b, hh, mm);
    const size_t off = (((size_t)blockIdx.x * 2 + ql) * 64 + lu) * 8;
    *(short8*)(vph + off) = hh;
    *(short8*)(vpm + off) = mm;
  }
}

// ---------------- triangular Gram v13: row-presummed scatter ----------------
// res[i] = sum_{j != i, fid >= 0.9} out[j]
// Base = R11-exact v11 ((256,2), always-3-product, v5 pass order).  v13
// changes ONLY the scatter: instead of 2 atomics per passing pair, presum
// contributions per TARGET ROW in registers and issue one atomic per distinct
// row per ballot.  i-side: per 16-lane group, vi = sum of out[js] over that
// group's bits -> 1 atomic to res[is].  j-side: per distinct column, vj = sum
// of out[is] over <=4 groups -> 1 atomic to res[js].  For clustered bits
// (fidelity cliques) this cuts atomic count up to 8x; never more than v11.
// Coverage identical (each i<j pair contributes out[j]->res[i], out[i]->res[j]
// exactly once); f32 presum regroups additions (order was already arbitrary).
__global__ __launch_bounds__(256, 2)
void gram_accum(const short* __restrict__ vph, const short* __restrict__ vpm,
                const float* __restrict__ out, float* __restrict__ res) {
  __shared__ __align__(16) short lAh[8 * 1024];   // 16 KB: A hi, 8 i-tiles
  __shared__ __align__(16) short lAm[8 * 1024];   // 16 KB: A mid
  const int tid = threadIdx.x;
  const int wave = tid >> 6, lane = tid & 63;

  // triangular decode: block t -> (I, Jc) with 0 <= I <= Jc < 64
  const int t = blockIdx.x;
  int I = (int)((129.0f - sqrtf(16641.0f - 8.0f * (float)t)) * 0.5f);
  if (I < 0) I = 0;
  while (64 * (I + 1) - ((I + 1) * I) / 2 <= t) ++I;
  while (64 * I - (I * (I - 1)) / 2 > t) --I;
  const int Jc = I + (t - (64 * I - (I * (I - 1)) / 2));
  const int i0 = I * 128;    // 8 i-tiles
  const int j0c = Jc * 128;  // 8 j-tiles

  // stage A hi+mid for the 8 i-tiles (32 KB): 32 wave-uniform 1KB items
  {
    const size_t base = (size_t)I * 8192;
#pragma unroll
    for (int u = 0; u < 8; ++u) {
      const int item = wave * 8 + u;
      const short* src;
      short* dst;
      if (item < 16) { src = vph + base + item * 512; dst = lAh + item * 512; }
      else           { src = vpm + base + (item - 16) * 512; dst = lAm + (item - 16) * 512; }
      __builtin_amdgcn_global_load_lds(
          (const __attribute__((address_space(1))) void*)(src + lane * 8),
          (__attribute__((address_space(3))) void*)dst, 16, 0, 0);
    }
  }
  __syncthreads();

#pragma unroll
  for (int tt = 0; tt < 2; ++tt) {
    const int jt = wave * 2 + tt;
    const int j0 = j0c + jt * 16;
    const short* jb_h = vph + (size_t)(j0 >> 4) * 1024;
    const short* jb_m = vpm + (size_t)(j0 >> 4) * 1024;
    short8 Bh0 = *(const short8*)(jb_h + lane * 8);
    short8 Bh1 = *(const short8*)(jb_h + 512 + lane * 8);
    short8 Bm0 = *(const short8*)(jb_m + lane * 8);
    short8 Bm1 = *(const short8*)(jb_m + 512 + lane * 8);

    f32x4 g[8];
#pragma unroll
    for (int it = 0; it < 8; ++it) g[it] = (f32x4){0.f, 0.f, 0.f, 0.f};
    // v5 pass order, unconditional; 8 independent chains per pass
#pragma unroll
    for (int it = 0; it < 8; ++it) {
      const short8 A0 = *(const short8*)(lAh + it * 1024 + lane * 8);
      g[it] = __builtin_amdgcn_mfma_f32_16x16x32_bf16(A0, Bh0, g[it], 0, 0, 0);
    }
#pragma unroll
    for (int it = 0; it < 8; ++it) {
      const short8 A1 = *(const short8*)(lAh + it * 1024 + 512 + lane * 8);
      g[it] = __builtin_amdgcn_mfma_f32_16x16x32_bf16(A1, Bh1, g[it], 0, 0, 0);
    }
#pragma unroll
    for (int it = 0; it < 8; ++it) {
      const short8 A0 = *(const short8*)(lAh + it * 1024 + lane * 8);
      g[it] = __builtin_amdgcn_mfma_f32_16x16x32_bf16(A0, Bm0, g[it], 0, 0, 0);
    }
#pragma unroll
    for (int it = 0; it < 8; ++it) {
      const short8 A1 = *(const short8*)(lAh + it * 1024 + 512 + lane * 8);
      g[it] = __builtin_amdgcn_mfma_f32_16x16x32_bf16(A1, Bm1, g[it], 0, 0, 0);
    }
#pragma unroll
    for (int it = 0; it < 8; ++it) {
      const short8 M0 = *(const short8*)(lAm + it * 1024 + lane * 8);
      g[it] = __builtin_amdgcn_mfma_f32_16x16x32_bf16(M0, Bh0, g[it], 0, 0, 0);
    }
#pragma unroll
    for (int it = 0; it < 8; ++it) {
      const short8 M1 = *(const short8*)(lAm + it * 1024 + 512 + lane * 8);
      g[it] = __builtin_amdgcn_mfma_f32_16x16x32_bf16(M1, Bh1, g[it], 0, 0, 0);
    }

    // ballot -> row-presummed mirrored scatter (i < j only)
    const int jl = j0 + (lane & 15);
#pragma unroll
    for (int it = 0; it < 8; ++it)
#pragma unroll
      for (int r = 0; r < 4; ++r) {
        const int il = i0 + it * 16 + (lane >> 4) * 4 + r;
        const unsigned long long m =
            __ballot((g[it][r] * g[it][r] >= THRESH) && (il != jl));
        if (m) {   // wave-uniform
          // i-side: one atomic per 16-lane group with any qualifying bit
#pragma unroll
          for (int gq = 0; gq < 4; ++gq) {
            unsigned mg = (unsigned)((m >> (16 * gq)) & 0xFFFFull);
            const int is = i0 + it * 16 + gq * 4 + r;
            float vi = 0.f;
            bool any = false;
            while (mg) {   // uniform
              const int c = __builtin_ctz(mg);
              mg &= mg - 1;
              const int js = j0 + c;
              if (is < js) { vi += out[(size_t)js * D_OUT + lane]; any = true; }
            }
            if (any) atomicAdd(res + (size_t)is * D_OUT + lane, vi);
          }
          // j-side: one atomic per distinct column with any qualifying bit
          unsigned cm = (unsigned)((m | (m >> 16) | (m >> 32) | (m >> 48)) & 0xFFFFull);
          while (cm) {   // uniform
            const int c = __builtin_ctz(cm);
            cm &= cm - 1;
            const int js = j0 + c;
            float vj = 0.f;
            bool any = false;
#pragma unroll
            for (int gq = 0; gq < 4; ++gq) {
              if ((m >> (16 * gq + c)) & 1ull) {
                const int is = i0 + it * 16 + gq * 4 + r;
                if (is < js) { vj += out[(size_t)is * D_OUT + lane]; any = true; }
              }
            }
            if (any) atomicAdd(res + (size_t)js * D_OUT + lane, vj);
          }
        }
      }
  }
}

// ---------------- launch ----------------
#define MB (1024 * 1024)
#define KB 1024

extern "C" void kernel_launch(void* const* d_in, const int* in_sizes, int n_in,
                              void* d_out, int out_size, void* d_ws, size_t ws_size,
                              hipStream_t stream) {
  const float* x  = (const float*)d_in[0];
  const float* W1 = (const float*)d_in[1];
  const float* b1 = (const float*)d_in[2];
  const float* W2 = (const float*)d_in[3];
  const float* b2 = (const float*)d_in[4];
  const float* W3 = (const float*)d_in[5];
  const float* b3 = (const float*)d_in[6];
  float* res = (float*)d_out;

  char* ws = (char*)d_ws;
  float* out = (float*)(ws);                     // 2 MB
  short* vph = (short*)(ws + 2 * MB);            // 1 MB
  short* vpm = (short*)(ws + 3 * MB);            // 1 MB
  short* w1h = (short*)(ws + 4 * MB);            // 256 KB
  short* w1m = (short*)(ws + 4 * MB + 256 * KB);
  short* w2h = (short*)(ws + 4 * MB + 512 * KB);
  short* w2m = (short*)(ws + 4 * MB + 768 * KB);
  short* w3h = (short*)(ws + 5 * MB);            // 32 KB
  short* w3m = (short*)(ws + 5 * MB + 32 * KB);

  // pack weights to fragment-major bf16 hi/mid (tiny, ~2.2 MB rw)
  wpack<<<136, 256, 0, stream>>>(W1, W2, W3, w1h, w1m, w2h, w2m, w3h, w3m);
  // fused MLP: 512 x 16-row blocks, R11-exact (512,4)
  fused_mlp16<<<512, 512, 0, stream>>>(x, w1h, w1m, b1, w2h, w2m, b2,
                                       w3h, w3m, b3, out, vph, vpm, res);
  // gram v13: triangular, always-3-product, row-presummed scatter
  gram_accum<<<dim3(2080), 256, 0, stream>>>(vph, vpm, out, res);
}

// Round 15
// 113.280 us; speedup vs baseline: 2.6075x; 2.6075x over previous
//
#include <hip/hip_runtime.h>
#include <hip/hip_bf16.h>
#include <math.h>

// Problem dims (fixed by reference)
#define B_ROWS 8192
#define D_IN   256
#define H1_DIM 512
#define H2_DIM 256
#define D_OUT  64
#define EPSF   1e-12f
#define THRESH 0.9f

typedef __attribute__((ext_vector_type(8))) short short8;   // 8 bf16 = 4 VGPR
typedef __attribute__((ext_vector_type(4))) float f32x4;

// fast tanh via hardware exp: tanh(|x|) = (1-e^{-2|x|})/(1+e^{-2|x|}), ~1e-7 rel err
__device__ inline float tanh_fast(float xx) {
  const float ax = fabsf(xx);
  const float t = __expf(-2.0f * ax);
  const float r = (1.0f - t) / (1.0f + t);
  return xx < 0.0f ? -r : r;
}

// split fp32x8 -> bf16 hi + bf16 mid (residual), fragment-packed
__device__ inline void splitf8(float4 a, float4 b, short8& h, short8& m) {
  float v[8] = {a.x, a.y, a.z, a.w, b.x, b.y, b.z, b.w};
  short h8[8], m8[8];
#pragma unroll
  for (int e = 0; e < 8; ++e) {
    __hip_bfloat16 hb = __float2bfloat16(v[e]);
    float hf = __bfloat162float(hb);
    __hip_bfloat16 mb = __float2bfloat16(v[e] - hf);
    h8[e] = *(short*)&hb;
    m8[e] = *(short*)&mb;
  }
  h = *(short8*)h8;
  m = *(short8*)m8;
}

// read 8 logical-consecutive floats at (row, kl) from an XOR-swizzled LDS buf.
// swizzle: dword index ^= (row&7)<<2 (16B-slot spread -> conflict-free b128)
__device__ inline void rd8_swz(const float* buf, int S, int row, int kl,
                               float4& a, float4& b) {
  const int xr = (row & 7) << 2;
  a = *(const float4*)&buf[(row * S + kl) ^ xr];
  b = *(const float4*)&buf[(row * S + kl + 4) ^ xr];
}

// ---------------- weight pre-pack (fragment-major bf16 hi/mid) ----------------
__device__ inline void pack8(const float* __restrict__ src, short* __restrict__ dh,
                             short* __restrict__ dm, int t, int C, int lgq) {
  const int lane = t & 63;
  const int g = t >> 6;
  const int q = g & ((1 << lgq) - 1);
  const int I = g >> lgq;
  const int row = I * 16 + (lane & 15);
  const int k0 = q * 32 + ((lane >> 4) << 3);
  const float* p = src + (size_t)row * C + k0;
  short8 hh, mm;
  splitf8(*(const float4*)p, *(const float4*)(p + 4), hh, mm);
  *(short8*)(dh + (size_t)t * 8) = hh;
  *(short8*)(dm + (size_t)t * 8) = mm;
}

__global__ __launch_bounds__(256)
void wpack(const float* __restrict__ W1, const float* __restrict__ W2,
           const float* __restrict__ W3,
           short* w1h, short* w1m, short* w2h, short* w2m,
           short* w3h, short* w3m) {
  const int b = blockIdx.x, tid = threadIdx.x;
  if (b < 64)        pack8(W1, w1h, w1m, b * 256 + tid, 256, 3);
  else if (b < 128)  pack8(W2, w2h, w2m, (b - 64) * 256 + tid, 512, 4);
  else               pack8(W3, w3h, w3m, (b - 128) * 256 + tid, 256, 3);
}

// ---------------- fully fused MLP, 16-row blocks (R11-exact, (512,4)) ----------------
__global__ __launch_bounds__(512, 4)
void fused_mlp16(const float* __restrict__ x,
                 const short* __restrict__ w1h, const short* __restrict__ w1m,
                 const float* __restrict__ b1,
                 const short* __restrict__ w2h, const short* __restrict__ w2m,
                 const float* __restrict__ b2,
                 const short* __restrict__ w3h, const short* __restrict__ w3m,
                 const float* __restrict__ b3,
                 float* __restrict__ out, short* __restrict__ vph,
                 short* __restrict__ vpm, float* __restrict__ res) {
  __shared__ __align__(16) char smem[49152];
  short* xph   = (short*)smem;                // 8KB
  short* xpm   = (short*)(smem + 8192);       // 8KB
  float* wbuf1 = (float*)smem;                // 16KB
  float* wbuf3 = (float*)smem;                // 4KB
  short* h1h   = (short*)(smem + 16384);      // 16KB
  short* h1m   = (short*)(smem + 32768);      // 16KB
  float* wbuf2 = (float*)(smem + 16384);      // 16KB
  short* h2ph  = (short*)(smem + 32768);      // 8KB
  short* h2pm  = (short*)(smem + 40960);      // 8KB
  __shared__ float nsum[16];
  __shared__ float invn[16];

  const int tid = threadIdx.x;
  const int wave = tid >> 6, lane = tid & 63;
  const int r0 = blockIdx.x * 16;
  const int col16 = lane & 15;
  const int rbase = (lane >> 4) << 2;   // C-layout row base

  // zero this block's res rows (harness poisons res): 16*64 = 256 float4
  if (tid < 256) {
    float4* rz = (float4*)(res + (size_t)r0 * D_OUT);
    rz[tid] = make_float4(0.f, 0.f, 0.f, 0.f);
  }

  // ---- pack x block (16x256 fp32 -> frag hi/mid): 512 units, 1/thread ----
  {
    const int lu = tid & 63, q = tid >> 6;
    const float* p = x + (size_t)(r0 + (lu & 15)) * D_IN + q * 32 + ((lu >> 4) << 3);
    short8 hh, mm;
    splitf8(*(const float4*)p, *(const float4*)(p + 4), hh, mm);
    const int off = (q * 64 + lu) * 8;
    *(short8*)(xph + off) = hh;
    *(short8*)(xpm + off) = mm;
  }
  __syncthreads();

  // ---- layer1: h1 = tanh(x @ W1^T + b1), N=512; wave owns 4 j-tiles ----
  f32x4 acc1[4];
#pragma unroll
  for (int jj = 0; jj < 4; ++jj) acc1[jj] = (f32x4){0.f, 0.f, 0.f, 0.f};
#pragma unroll 4
  for (int q = 0; q < 8; ++q) {
    const int aoff = (q * 64 + lane) * 8;
    const short8 Ah = *(const short8*)(xph + aoff);
    const short8 Am = *(const short8*)(xpm + aoff);
#pragma unroll
    for (int jj = 0; jj < 4; ++jj) {
      const int boff = (((wave * 4 + jj) * 8 + q) * 64 + lane) * 8;
      const short8 Bh = *(const short8*)(w1h + boff);
      const short8 Bm = *(const short8*)(w1m + boff);
      acc1[jj] = __builtin_amdgcn_mfma_f32_16x16x32_bf16(Ah, Bh, acc1[jj], 0, 0, 0);
      acc1[jj] = __builtin_amdgcn_mfma_f32_16x16x32_bf16(Ah, Bm, acc1[jj], 0, 0, 0);
      acc1[jj] = __builtin_amdgcn_mfma_f32_16x16x32_bf16(Am, Bh, acc1[jj], 0, 0, 0);
    }
  }
  __syncthreads();   // xp dead; [0,16K) becomes wbuf1

  // ---- L1 epilogue: two 256-col halves through swizzled wbuf1 ----
  float bv1[4];
#pragma unroll
  for (int jj = 0; jj < 4; ++jj) bv1[jj] = b1[(wave * 4 + jj) * 16 + col16];
#pragma unroll
  for (int h = 0; h < 2; ++h) {
    if ((wave >> 2) == h) {
#pragma unroll
      for (int jj = 0; jj < 4; ++jj)
#pragma unroll
        for (int r = 0; r < 4; ++r) {
          const int row = rbase + r;
          const int col = ((wave & 3) * 4 + jj) * 16 + col16;   // [0,256)
          wbuf1[(row * 256 + col) ^ ((row & 7) << 2)] = tanh_fast(acc1[jj][r] + bv1[jj]);
        }
    }
    __syncthreads();
    {
      const int lu = tid & 63, ql = tid >> 6;
      const int row = lu & 15, kl = ql * 32 + ((lu >> 4) << 3);
      float4 a, b;
      rd8_swz(wbuf1, 256, row, kl, a, b);
      short8 hh, mm;
      splitf8(a, b, hh, mm);
      const int off = ((h * 8 + ql) * 64 + lu) * 8;
      *(short8*)(h1h + off) = hh;
      *(short8*)(h1m + off) = mm;
    }
    __syncthreads();
  }

  // ---- layer2: h2 = tanh(h1 @ W2^T + b2), N=256; wave owns 2 j-tiles ----
  f32x4 acc2[2];
#pragma unroll
  for (int jj = 0; jj < 2; ++jj) acc2[jj] = (f32x4){0.f, 0.f, 0.f, 0.f};
#pragma unroll 4
  for (int q = 0; q < 16; ++q) {
    const int aoff = (q * 64 + lane) * 8;
    const short8 Ah = *(const short8*)(h1h + aoff);
    const short8 Am = *(const short8*)(h1m + aoff);
#pragma unroll
    for (int jj = 0; jj < 2; ++jj) {
      const int boff = (((wave * 2 + jj) * 16 + q) * 64 + lane) * 8;
      const short8 Bh = *(const short8*)(w2h + boff);
      const short8 Bm = *(const short8*)(w2m + boff);
      acc2[jj] = __builtin_amdgcn_mfma_f32_16x16x32_bf16(Ah, Bh, acc2[jj], 0, 0, 0);
      acc2[jj] = __builtin_amdgcn_mfma_f32_16x16x32_bf16(Ah, Bm, acc2[jj], 0, 0, 0);
      acc2[jj] = __builtin_amdgcn_mfma_f32_16x16x32_bf16(Am, Bh, acc2[jj], 0, 0, 0);
    }
  }
  __syncthreads();   // h1 dead; [16K,32K) becomes wbuf2

  // ---- L2 epilogue ----
  {
    float bv2[2];
#pragma unroll
    for (int jj = 0; jj < 2; ++jj) bv2[jj] = b2[(wave * 2 + jj) * 16 + col16];
#pragma unroll
    for (int jj = 0; jj < 2; ++jj)
#pragma unroll
      for (int r = 0; r < 4; ++r) {
        const int row = rbase + r;
        const int col = (wave * 2 + jj) * 16 + col16;   // [0,256)
        wbuf2[(row * 256 + col) ^ ((row & 7) << 2)] = tanh_fast(acc2[jj][r] + bv2[jj]);
      }
  }
  __syncthreads();
  {
    const int lu = tid & 63, ql = tid >> 6;
    const int row = lu & 15, kl = ql * 32 + ((lu >> 4) << 3);
    float4 a, b;
    rd8_swz(wbuf2, 256, row, kl, a, b);
    short8 hh, mm;
    splitf8(a, b, hh, mm);
    const int off = (ql * 64 + lu) * 8;
    *(short8*)(h2ph + off) = hh;
    *(short8*)(h2pm + off) = mm;
  }
  __syncthreads();

  // ---- layer3: out = h2 @ W3^T + b3, N=64; waves 0-3 ----
  if (wave < 4) {
    f32x4 acc3 = (f32x4){0.f, 0.f, 0.f, 0.f};
#pragma unroll 4
    for (int q = 0; q < 8; ++q) {
      const int aoff = (q * 64 + lane) * 8;
      const short8 Ah = *(const short8*)(h2ph + aoff);
      const short8 Am = *(const short8*)(h2pm + aoff);
      const int boff = ((wave * 8 + q) * 64 + lane) * 8;
      const short8 Bh = *(const short8*)(w3h + boff);
      const short8 Bm = *(const short8*)(w3m + boff);
      acc3 = __builtin_amdgcn_mfma_f32_16x16x32_bf16(Ah, Bh, acc3, 0, 0, 0);
      acc3 = __builtin_amdgcn_mfma_f32_16x16x32_bf16(Ah, Bm, acc3, 0, 0, 0);
      acc3 = __builtin_amdgcn_mfma_f32_16x16x32_bf16(Am, Bh, acc3, 0, 0, 0);
    }
    const float bv3 = b3[wave * 16 + col16];
#pragma unroll
    for (int r = 0; r < 4; ++r) {
      const int row = rbase + r;
      const int col = wave * 16 + col16;   // [0,64)
      wbuf3[(row * 64 + col) ^ ((row & 7) << 2)] = acc3[r] + bv3;
    }
  }
  __syncthreads();

  // ---- row norms: 16 threads/row x 4 cols ----
  if (tid < 256) {
    const int row = tid >> 4, c4 = (tid & 15) * 4;
    const float4 a = *(const float4*)&wbuf3[(row * 64 + c4) ^ ((row & 7) << 2)];
    float s = a.x * a.x + a.y * a.y + a.z * a.z + a.w * a.w;
    s += __shfl_xor(s, 1, 64);
    s += __shfl_xor(s, 2, 64);
    s += __shfl_xor(s, 4, 64);
    s += __shfl_xor(s, 8, 64);
    if ((tid & 15) == 0) nsum[row] = s;
  }
  __syncthreads();
  if (tid < 16) invn[tid] = 1.0f / (sqrtf(nsum[tid]) + EPSF);
  __syncthreads();

  // ---- write out (fp32) ----
  if (tid < 256) {
    const int row = tid >> 4, c4 = (tid & 15) * 4;
    *(float4*)(out + (size_t)(r0 + row) * D_OUT + c4) =
        *(const float4*)&wbuf3[(row * 64 + c4) ^ ((row & 7) << 2)];
  }
  // ---- write normalized split-pack vph/vpm (gram operand) ----
  if (tid < 128) {
    const int lu = tid & 63, ql = tid >> 6;
    const int row = lu & 15, kl = ql * 32 + ((lu >> 4) << 3);
    const float sc = invn[row];
    float4 a, b;
    rd8_swz(wbuf3, 64, row, kl, a, b);
    a.x *= sc; a.y *= sc; a.z *= sc; a.w *= sc;
    b.x *= sc; b.y *= sc; b.z *= sc; b.w *= sc;
    short8 hh, mm;
    splitf8(a, b, hh, mm);
    const size_t off = (((size_t)blockIdx.x * 2 + ql) * 64 + lu) * 8;
    *(short8*)(vph + off) = hh;
    *(short8*)(vpm + off) = mm;
  }
}

// ---------------- triangular Gram v11 (R11-exact, measured best) ----------------
// res[i] = sum_{j != i, fid >= 0.9} out[j]
// Triangular 2080 blocks; always-3-product split dot (AhBh+AhBm+AmBh) in the
// v5 pass order; ballot + wave-cooperative mirrored global-atomic scatter.
// R12-14 variants (occupancy caps, i-halving, presummed scatter) all
// regressed — this is the measured-best gram configuration (114.9 us total).
__global__ __launch_bounds__(256, 2)
void gram_accum(const short* __restrict__ vph, const short* __restrict__ vpm,
                const float* __restrict__ out, float* __restrict__ res) {
  __shared__ __align__(16) short lAh[8 * 1024];   // 16 KB: A hi, 8 i-tiles
  __shared__ __align__(16) short lAm[8 * 1024];   // 16 KB: A mid
  const int tid = threadIdx.x;
  const int wave = tid >> 6, lane = tid & 63;

  // triangular decode: block t -> (I, Jc) with 0 <= I <= Jc < 64
  const int t = blockIdx.x;
  int I = (int)((129.0f - sqrtf(16641.0f - 8.0f * (float)t)) * 0.5f);
  if (I < 0) I = 0;
  while (64 * (I + 1) - ((I + 1) * I) / 2 <= t) ++I;
  while (64 * I - (I * (I - 1)) / 2 > t) --I;
  const int Jc = I + (t - (64 * I - (I * (I - 1)) / 2));
  const int i0 = I * 128;    // 8 i-tiles
  const int j0c = Jc * 128;  // 8 j-tiles

  // stage A hi+mid for the 8 i-tiles (32 KB): 32 wave-uniform 1KB items
  {
    const size_t base = (size_t)I * 8192;
#pragma unroll
    for (int u = 0; u < 8; ++u) {
      const int item = wave * 8 + u;
      const short* src;
      short* dst;
      if (item < 16) { src = vph + base + item * 512; dst = lAh + item * 512; }
      else           { src = vpm + base + (item - 16) * 512; dst = lAm + (item - 16) * 512; }
      __builtin_amdgcn_global_load_lds(
          (const __attribute__((address_space(1))) void*)(src + lane * 8),
          (__attribute__((address_space(3))) void*)dst, 16, 0, 0);
    }
  }
  __syncthreads();

#pragma unroll
  for (int tt = 0; tt < 2; ++tt) {
    const int jt = wave * 2 + tt;
    const int j0 = j0c + jt * 16;
    const short* jb_h = vph + (size_t)(j0 >> 4) * 1024;
    const short* jb_m = vpm + (size_t)(j0 >> 4) * 1024;
    short8 Bh0 = *(const short8*)(jb_h + lane * 8);
    short8 Bh1 = *(const short8*)(jb_h + 512 + lane * 8);
    short8 Bm0 = *(const short8*)(jb_m + lane * 8);
    short8 Bm1 = *(const short8*)(jb_m + 512 + lane * 8);

    f32x4 g[8];
#pragma unroll
    for (int it = 0; it < 8; ++it) g[it] = (f32x4){0.f, 0.f, 0.f, 0.f};
    // v5 pass order, unconditional; 8 independent chains per pass
#pragma unroll
    for (int it = 0; it < 8; ++it) {
      const short8 A0 = *(const short8*)(lAh + it * 1024 + lane * 8);
      g[it] = __builtin_amdgcn_mfma_f32_16x16x32_bf16(A0, Bh0, g[it], 0, 0, 0);
    }
#pragma unroll
    for (int it = 0; it < 8; ++it) {
      const short8 A1 = *(const short8*)(lAh + it * 1024 + 512 + lane * 8);
      g[it] = __builtin_amdgcn_mfma_f32_16x16x32_bf16(A1, Bh1, g[it], 0, 0, 0);
    }
#pragma unroll
    for (int it = 0; it < 8; ++it) {
      const short8 A0 = *(const short8*)(lAh + it * 1024 + lane * 8);
      g[it] = __builtin_amdgcn_mfma_f32_16x16x32_bf16(A0, Bm0, g[it], 0, 0, 0);
    }
#pragma unroll
    for (int it = 0; it < 8; ++it) {
      const short8 A1 = *(const short8*)(lAh + it * 1024 + 512 + lane * 8);
      g[it] = __builtin_amdgcn_mfma_f32_16x16x32_bf16(A1, Bm1, g[it], 0, 0, 0);
    }
#pragma unroll
    for (int it = 0; it < 8; ++it) {
      const short8 M0 = *(const short8*)(lAm + it * 1024 + lane * 8);
      g[it] = __builtin_amdgcn_mfma_f32_16x16x32_bf16(M0, Bh0, g[it], 0, 0, 0);
    }
#pragma unroll
    for (int it = 0; it < 8; ++it) {
      const short8 M1 = *(const short8*)(lAm + it * 1024 + 512 + lane * 8);
      g[it] = __builtin_amdgcn_mfma_f32_16x16x32_bf16(M1, Bh1, g[it], 0, 0, 0);
    }

    // ballot + wave-cooperative mirrored scatter (i < j only)
    const int jl = j0 + (lane & 15);
#pragma unroll
    for (int it = 0; it < 8; ++it)
#pragma unroll
      for (int r = 0; r < 4; ++r) {
        const int il = i0 + it * 16 + (lane >> 4) * 4 + r;
        unsigned long long m =
            __ballot((g[it][r] * g[it][r] >= THRESH) && (il != jl));
        while (m) {
          const int s = __builtin_ctzll(m);
          m &= m - 1;
          const int js = j0 + (s & 15);
          const int is = i0 + it * 16 + ((s >> 4) << 2) + r;
          if (is < js) {
            atomicAdd(res + (size_t)is * D_OUT + lane, out[(size_t)js * D_OUT + lane]);
            atomicAdd(res + (size_t)js * D_OUT + lane, out[(size_t)is * D_OUT + lane]);
          }
        }
      }
  }
}

// ---------------- launch ----------------
#define MB (1024 * 1024)
#define KB 1024

extern "C" void kernel_launch(void* const* d_in, const int* in_sizes, int n_in,
                              void* d_out, int out_size, void* d_ws, size_t ws_size,
                              hipStream_t stream) {
  const float* x  = (const float*)d_in[0];
  const float* W1 = (const float*)d_in[1];
  const float* b1 = (const float*)d_in[2];
  const float* W2 = (const float*)d_in[3];
  const float* b2 = (const float*)d_in[4];
  const float* W3 = (const float*)d_in[5];
  const float* b3 = (const float*)d_in[6];
  float* res = (float*)d_out;

  char* ws = (char*)d_ws;
  float* out = (float*)(ws);                     // 2 MB
  short* vph = (short*)(ws + 2 * MB);            // 1 MB
  short* vpm = (short*)(ws + 3 * MB);            // 1 MB
  short* w1h = (short*)(ws + 4 * MB);            // 256 KB
  short* w1m = (short*)(ws + 4 * MB + 256 * KB);
  short* w2h = (short*)(ws + 4 * MB + 512 * KB);
  short* w2m = (short*)(ws + 4 * MB + 768 * KB);
  short* w3h = (short*)(ws + 5 * MB);            // 32 KB
  short* w3m = (short*)(ws + 5 * MB + 32 * KB);

  // pack weights to fragment-major bf16 hi/mid (tiny, ~2.2 MB rw)
  wpack<<<136, 256, 0, stream>>>(W1, W2, W3, w1h, w1m, w2h, w2m, w3h, w3m);
  // fused MLP: 512 x 16-row blocks, 2 blocks/CU (R11-exact)
  fused_mlp16<<<512, 512, 0, stream>>>(x, w1h, w1m, b1, w2h, w2m, b2,
                                       w3h, w3m, b3, out, vph, vpm, res);
  // gram v11: triangular, always-3-product, mirrored scatter (R11-exact)
  gram_accum<<<dim3(2080), 256, 0, stream>>>(vph, vpm, out, res);
}